// Round 15
// baseline (222.238 us; speedup 1.0000x reference)
//
#include <hip/hip_runtime.h>
#include <math.h>

#define SMK    2048
#define TAPS   32
#define OUTLEN (SMK + TAPS - 1)   // 2079
#define PAD    32
#define SLOTS  (PAD + SMK + PAD)  // 2112 float2 slots
#define NF4    (SLOTS / 2)        // 1056 float4 slots, LINEAR
#define MDFT   64
#define ROWS_PER_BLOCK 8
#define NBLOCKS 2048              // * ROWS_PER_BLOCK = 16384 rows

typedef float v2f __attribute__((ext_vector_type(2)));

__device__ __forceinline__ float rfl(float x) {
    return __int_as_float(__builtin_amdgcn_readfirstlane(__float_as_int(x)));
}

// r11 core (135.6 us) + persistent-block row pipeline:
//  - signal prefetch into 16 VGPRs, issued AFTER the post-stage barrier
//    (flies under compute; drained by next iteration's stage barrier)
//  - tap prefetch via LDS double-buffer (zero VGPR footprint; also removes
//    r11's 256-thread-redundant tap loads)
//  - plain float2 stores (r14 proved asm dwordx4 fusion regresses)
__global__ __launch_bounds__(256, 8)
void conv_kernel(const float* __restrict__ input,
                 const float* __restrict__ cof,
                 float* __restrict__ out0,
                 float* __restrict__ out1)
{
    __shared__ float4 S4[NF4];
    __shared__ float2 s_tw[MDFT];
    __shared__ float2 s_tap[2][TAPS];

    const int tid = threadIdx.x;

    // One-time: zero pads + DFT twiddles.
    if (tid < 16) {
        S4[tid] = make_float4(0.f, 0.f, 0.f, 0.f);            // front pad
    } else if (tid < 32) {
        S4[1024 + tid] = make_float4(0.f, 0.f, 0.f, 0.f);     // back pad
    }
    if (tid >= 64 && tid < 128) {
        int j = tid - 64;
        float sv, cv;
        __sincosf(-2.0f * (float)M_PI * (float)j / (float)MDFT, &sv, &cv);
        s_tw[j] = make_float2(cv, sv);
    }

    // Prologue: row 0 signal -> stg, row 0 taps -> s_tap[0].
    float4 stg[4];
    {
        const float4* g = (const float4*)(input + (size_t)blockIdx.x * (SMK * 2));
        #pragma unroll
        for (int k = 0; k < 4; ++k) stg[k] = g[tid + 256 * k];
        if (tid < TAPS) {
            const float2* ct = (const float2*)(cof + (size_t)blockIdx.x * (TAPS * 2));
            s_tap[0][tid] = ct[tid];
        }
    }

    #pragma unroll 1
    for (int it = 0; it < ROWS_PER_BLOCK; ++it) {
        const size_t r = (size_t)blockIdx.x + (size_t)NBLOCKS * it;

        __syncthreads();   // (a) prior row's LDS reads done; prefetch drained
        #pragma unroll
        for (int k = 0; k < 4; ++k) S4[16 + tid + 256 * k] = stg[k];
        __syncthreads();   // (b) S4 + s_tap[it&1] ready; stg regs free

        // Taps -> SGPR from LDS (broadcast reads, block-uniform values).
        float hre[TAPS], him[TAPS];
        #pragma unroll
        for (int l = 0; l < TAPS; ++l) {
            float2 tv = s_tap[it & 1][l];
            hre[l] = rfl(tv.x);
            him[l] = rfl(tv.y);
        }

        // Prefetch row r+1: signal into stg (in flight under compute),
        // taps into the other LDS buffer (lanes 0..31 of wave 0 only).
        if (it + 1 < ROWS_PER_BLOCK) {
            const float4* gn = (const float4*)(input + (r + NBLOCKS) * (size_t)(SMK * 2));
            #pragma unroll
            for (int k = 0; k < 4; ++k) stg[k] = gn[tid + 256 * k];
            if (tid < TAPS) {
                const float2* ctn = (const float2*)(cof + (r + NBLOCKS) * (size_t)(TAPS * 2));
                s_tap[(it + 1) & 1][tid] = ctn[tid];
            }
        }

        float2* go2 = (float2*)(out0 + r * (size_t)(OUTLEN * 2));

        // ---- main: outputs t = 2*tid+1+512*j + k, k<2 (r11 core verbatim) ----
        #pragma unroll 1
        for (int j = 0; j < 4; ++j) {
            const int t0 = 2 * tid + 1 + 512 * j;

            v2f accA[2], accB[2];
            #pragma unroll
            for (int k = 0; k < 2; ++k) { accA[k] = (v2f)(0.f); accB[k] = (v2f)(0.f); }

            #pragma unroll
            for (int c = 0; c < 4; ++c) {
                const int base4 = tid + 13 + 256 * j - 4 * c;
                float4 w4[5];
                #pragma unroll
                for (int i = 0; i < 5; ++i) w4[i] = S4[base4 + i];

                #pragma unroll
                for (int lp = 0; lp < 8; ++lp) {
                    const int l = 8 * c + lp;
                    const v2f hv = { hre[l], him[l] };     // SGPR pair, uniform
                    #pragma unroll
                    for (int k = 0; k < 2; ++k) {
                        const int m = k - lp + 7;          // 0..8, compile-time
                        const float sx = (m & 1) ? w4[m >> 1].z : w4[m >> 1].x;
                        const float sy = (m & 1) ? w4[m >> 1].w : w4[m >> 1].y;
                        accA[k] = __builtin_elementwise_fma((v2f){ sx, sx }, hv, accA[k]);
                        accB[k] = __builtin_elementwise_fma((v2f){ sy, sy }, hv, accB[k]);
                    }
                }
                __builtin_amdgcn_sched_barrier(0);   // contain chunk live-ranges
            }

            go2[t0]     = make_float2(accA[0].x - accB[0].y, accA[0].y + accB[0].x);
            go2[t0 + 1] = make_float2(accA[1].x - accB[1].y, accA[1].y + accB[1].x);
        }

        const float2* S2 = (const float2*)S4;

        // ---- wave 0: fused 64-pt DFT of zero-padded taps ----
        if (tid < MDFT) {
            const int kk = tid;
            v2f aA = (v2f)(0.f), aB = (v2f)(0.f);
            #pragma unroll
            for (int l = 0; l < TAPS; ++l) {
                const v2f hv = { hre[l], him[l] };
                float2 w = s_tw[(kk * l) & (MDFT - 1)];
                aA = __builtin_elementwise_fma((v2f){ w.x, w.x }, hv, aA);
                aB = __builtin_elementwise_fma((v2f){ w.y, w.y }, hv, aB);
            }
            ((float2*)out1)[r * MDFT + kk] = make_float2(aA.x - aB.y, aA.y + aB.x);
        }
        // ---- wave 2: leftover outputs t=0 and t=2049..2078 ----
        else if (tid >= 128 && tid <= 158) {
            const int t = (tid == 158) ? 0 : (2049 + (tid - 128));
            v2f aA = (v2f)(0.f), aB = (v2f)(0.f);
            #pragma unroll
            for (int l = 0; l < TAPS; ++l) {
                const v2f hv = { hre[l], him[l] };
                float2 s = S2[PAD + t - l];      // pads supply zeros both ends
                aA = __builtin_elementwise_fma((v2f){ s.x, s.x }, hv, aA);
                aB = __builtin_elementwise_fma((v2f){ s.y, s.y }, hv, aB);
            }
            go2[t] = make_float2(aA.x - aB.y, aA.y + aB.x);
        }
    }
}

extern "C" void kernel_launch(void* const* d_in, const int* in_sizes, int n_in,
                              void* d_out, int out_size, void* d_ws, size_t ws_size,
                              hipStream_t stream)
{
    const float* input = (const float*)d_in[0];  // (N,P,2048,2) fp32
    const float* cof   = (const float*)d_in[1];  // (N,P,32,2)   fp32
    // d_in[2] is M (=64), compile-time here.

    float* out0 = (float*)d_out;                                   // (NP, 2079, 2)
    const int NP = in_sizes[0] / (SMK * 2);                        // 16384
    float* out1 = out0 + (size_t)NP * OUTLEN * 2;                  // (NP, 64, 2)

    conv_kernel<<<NBLOCKS, 256, 0, stream>>>(input, cof, out0, out1);
}

// Round 16
// 171.679 us; speedup vs baseline: 1.2945x; 1.2945x over previous
//
#include <hip/hip_runtime.h>
#include <math.h>

#define SMK    2048
#define TAPS   32
#define OUTLEN (SMK + TAPS - 1)   // 2079
#define PAD    32
#define SLOTS  (PAD + SMK + PAD)  // 2112 float2 slots
#define NF4    (SLOTS / 2)        // 1056 float4 slots, LINEAR
#define MDFT   64

typedef float v2f __attribute__((ext_vector_type(2)));

__device__ __forceinline__ float rfl(float x) {
    return __int_as_float(__builtin_amdgcn_readfirstlane(__float_as_int(x)));
}

// r11 core, with the output pair placed at a 16B-aligned address:
// element t of row r is 16B-aligned iff t ≡ r (mod 2), so the pair start is
// t0 = 2*tid + 1 + S + 512j with S = (row even ? 1 : 0). The two outputs then
// store as ONE naturally-aligned float4 (plain C++ -> global_store_dwordx4,
// no asm, no fences): store line-touches drop 512 -> 256/block (the floor).
// Window reads stay 5 ds_read_b128 per chunk; only the compile-time pick
// index shifts: q = k - lp + 7 + S (f4 window covers slots base4..base4+4).
template <int S>
__device__ __forceinline__ void conv_core(
    const float4* __restrict__ S4, const float* hre, const float* him,
    float2* __restrict__ go2, int tid)
{
    #pragma unroll 1
    for (int j = 0; j < 4; ++j) {
        const int t0 = 2 * tid + 1 + S + 512 * j;

        v2f accA[2], accB[2];
        #pragma unroll
        for (int k = 0; k < 2; ++k) { accA[k] = (v2f)(0.f); accB[k] = (v2f)(0.f); }

        #pragma unroll
        for (int c = 0; c < 4; ++c) {
            // f2 window for chunk c starts at PAD+t0-8c-7 (parity = S);
            // f4 base covers it for both parities with the same formula:
            const int base4 = tid + 13 + 256 * j - 4 * c;
            float4 w4[5];
            #pragma unroll
            for (int i = 0; i < 5; ++i) w4[i] = S4[base4 + i];

            #pragma unroll
            for (int lp = 0; lp < 8; ++lp) {
                const int l = 8 * c + lp;
                const v2f hv = { hre[l], him[l] };     // SGPR pair, uniform
                #pragma unroll
                for (int k = 0; k < 2; ++k) {
                    const int q = k - lp + 7 + S;      // 0..9, compile-time
                    const float sx = (q & 1) ? w4[q >> 1].z : w4[q >> 1].x;
                    const float sy = (q & 1) ? w4[q >> 1].w : w4[q >> 1].y;
                    accA[k] = __builtin_elementwise_fma((v2f){ sx, sx }, hv, accA[k]);
                    accB[k] = __builtin_elementwise_fma((v2f){ sy, sy }, hv, accB[k]);
                }
            }
            __builtin_amdgcn_sched_barrier(0);   // contain chunk live-ranges
        }

        // One 16B-aligned float4 store per pair (aligned by construction).
        *reinterpret_cast<float4*>(&go2[t0]) =
            make_float4(accA[0].x - accB[0].y, accA[0].y + accB[0].x,
                        accA[1].x - accB[1].y, accA[1].y + accB[1].x);
    }
}

__global__ __launch_bounds__(256, 8)
void conv_kernel(const float* __restrict__ input,
                 const float* __restrict__ cof,
                 float* __restrict__ out0,
                 float* __restrict__ out1)
{
    __shared__ float4 S4[NF4];
    __shared__ float2 s_tw[MDFT];

    const int tid = threadIdx.x;
    const int row = blockIdx.x;

    // ---- stage signal row (16 KB) into linear LDS ----
    const float4* gin = (const float4*)(input + (size_t)row * (SMK * 2));
    #pragma unroll
    for (int k = 0; k < 4; ++k) S4[16 + tid + 256 * k] = gin[tid + 256 * k];
    if (tid < 16) {
        S4[tid] = make_float4(0.f, 0.f, 0.f, 0.f);            // front pad
    } else if (tid < 32) {
        S4[1024 + tid] = make_float4(0.f, 0.f, 0.f, 0.f);     // back pad
    }
    if (tid >= 64 && tid < 128) {                             // twiddles
        int j = tid - 64;
        float sv, cv;
        __sincosf(-2.0f * (float)M_PI * (float)j / (float)MDFT, &sv, &cv);
        s_tw[j] = make_float2(cv, sv);
    }

    // ---- taps -> SGPR (block-uniform) ----
    const float2* __restrict__ ct = (const float2*)(cof + (size_t)row * (TAPS * 2));
    float hre[TAPS], him[TAPS];
    #pragma unroll
    for (int l = 0; l < TAPS; ++l) {
        float2 tv = ct[l];
        hre[l] = rfl(tv.x);
        him[l] = rfl(tv.y);
    }
    __syncthreads();

    float2* go2 = (float2*)(out0 + (size_t)row * (OUTLEN * 2));

    // Main coverage: S=0 (odd rows): t in [1,2048]; S=1 (even rows): [2,2049].
    if (row & 1) conv_core<0>(S4, hre, him, go2, tid);
    else         conv_core<1>(S4, hre, him, go2, tid);

    const float2* S2 = (const float2*)S4;

    // ---- wave 0: fused 64-pt DFT of zero-padded taps (all 64 bins) ----
    if (tid < MDFT) {
        const int kk = tid;
        v2f aA = (v2f)(0.f), aB = (v2f)(0.f);
        #pragma unroll
        for (int l = 0; l < TAPS; ++l) {
            const v2f hv = { hre[l], him[l] };
            float2 w = s_tw[(kk * l) & (MDFT - 1)];
            aA = __builtin_elementwise_fma((v2f){ w.x, w.x }, hv, aA);
            aB = __builtin_elementwise_fma((v2f){ w.y, w.y }, hv, aB);
        }
        ((float2*)out1)[(size_t)row * MDFT + kk] =
            make_float2(aA.x - aB.y, aA.y + aB.x);
    }
    // ---- wave 2: leftover outputs (31 per row, parity-dependent) ----
    else if (tid >= 128 && tid <= 158) {
        int t;
        if (row & 1) {               // S=0: leftovers are 0, 2049..2078
            t = (tid == 158) ? 0 : (2049 + (tid - 128));
        } else {                     // S=1: leftovers are 0, 1, 2050..2078
            t = (tid == 158) ? 0 : (tid == 157) ? 1 : (2050 + (tid - 128));
        }
        v2f aA = (v2f)(0.f), aB = (v2f)(0.f);
        #pragma unroll
        for (int l = 0; l < TAPS; ++l) {
            const v2f hv = { hre[l], him[l] };
            float2 s = S2[PAD + t - l];      // pads supply zeros both ends
            aA = __builtin_elementwise_fma((v2f){ s.x, s.x }, hv, aA);
            aB = __builtin_elementwise_fma((v2f){ s.y, s.y }, hv, aB);
        }
        go2[t] = make_float2(aA.x - aB.y, aA.y + aB.x);
    }
}

extern "C" void kernel_launch(void* const* d_in, const int* in_sizes, int n_in,
                              void* d_out, int out_size, void* d_ws, size_t ws_size,
                              hipStream_t stream)
{
    const float* input = (const float*)d_in[0];  // (N,P,2048,2) fp32
    const float* cof   = (const float*)d_in[1];  // (N,P,32,2)   fp32
    // d_in[2] is M (=64), compile-time here.

    const int NP = in_sizes[0] / (SMK * 2);      // 16384

    float* out0 = (float*)d_out;                           // (NP, 2079, 2)
    float* out1 = out0 + (size_t)NP * OUTLEN * 2;          // (NP, 64, 2)

    conv_kernel<<<NP, 256, 0, stream>>>(input, cof, out0, out1);
}

// Round 17
// 156.762 us; speedup vs baseline: 1.4177x; 1.0952x over previous
//
#include <hip/hip_runtime.h>
#include <math.h>

#define SMK    2048
#define TAPS   32
#define OUTLEN (SMK + TAPS - 1)   // 2079
#define PAD    32
#define SLOTS  (PAD + SMK + PAD)  // 2112 float2 slots
#define NF4    (SLOTS / 2)        // 1056 float4 slots, LINEAR
#define MDFT   64
#define RPB    8                  // rows per block
#define NBLOCKS 2048              // * RPB = 16384 rows

typedef float v2f __attribute__((ext_vector_type(2)));

__device__ __forceinline__ float rfl(float x) {
    return __int_as_float(__builtin_amdgcn_readfirstlane(__float_as_int(x)));
}

// Async global->LDS, 16B per lane. LDS dest is wave-uniform base + lane*16
// (HW rule); global src is per-lane. No VGPR round-trip, no live range ->
// the register-allocator failure mode of r4/r5/r7/r15 is structurally gone.
__device__ __forceinline__ void gload16(const void* g, void* l) {
    __builtin_amdgcn_global_load_lds(
        (const __attribute__((address_space(1))) void*)g,
        (__attribute__((address_space(3))) void*)l, 16, 0, 0);
}

__global__ __launch_bounds__(256)
void conv_kernel(const float* __restrict__ input,
                 const float* __restrict__ cof,
                 float* __restrict__ out0,
                 float* __restrict__ out1)
{
    __shared__ float4 SS[2][NF4];          // double-buffered signal rows
    __shared__ float2 s_tw[MDFT];
    __shared__ float2 s_tap[RPB][TAPS];    // all 8 rows' taps, staged once

    const int tid = threadIdx.x;
    const int wid = tid >> 6;              // wave id (uniform in wave)
    const int bid = blockIdx.x;

    // ---- prologue: pads (both buffers), twiddles, all taps, row-0 signal ----
    if (tid < 16) {
        SS[0][tid] = make_float4(0.f, 0.f, 0.f, 0.f);
        SS[1][tid] = make_float4(0.f, 0.f, 0.f, 0.f);
    } else if (tid < 32) {
        SS[0][1024 + tid] = make_float4(0.f, 0.f, 0.f, 0.f);
        SS[1][1024 + tid] = make_float4(0.f, 0.f, 0.f, 0.f);
    }
    if (tid >= 64 && tid < 128) {
        int j = tid - 64;
        float sv, cv;
        __sincosf(-2.0f * (float)M_PI * (float)j / (float)MDFT, &sv, &cv);
        s_tw[j] = make_float2(cv, sv);
    }
    if (tid < TAPS) {
        #pragma unroll
        for (int it = 0; it < RPB; ++it) {
            const float2* ct = (const float2*)(cof +
                ((size_t)bid + (size_t)NBLOCKS * it) * (TAPS * 2));
            s_tap[it][tid] = ct[tid];
        }
    }
    {   // row 0 signal -> SS[0], async
        const float4* g = (const float4*)(input + (size_t)bid * (SMK * 2)) + tid;
        #pragma unroll
        for (int k = 0; k < 4; ++k)
            gload16(g + 256 * k, &SS[0][16 + 64 * wid + 256 * k]);
    }

    int cur = 0;
    #pragma unroll 1
    for (int it = 0; it < RPB; ++it) {
        const size_t r = (size_t)bid + (size_t)NBLOCKS * it;

        // Barrier drains vmcnt(0): SS[cur]'s async writes have landed, and
        // (it>0) all waves finished reading SS[cur^1] -> safe to overwrite.
        __syncthreads();

        // Issue next row's staging NOW; it flies under this row's compute
        // and is consumed by the NEXT iteration's barrier drain.
        if (it + 1 < RPB) {
            const float4* gn = (const float4*)(input +
                (r + NBLOCKS) * (size_t)(SMK * 2)) + tid;
            #pragma unroll
            for (int k = 0; k < 4; ++k)
                gload16(gn + 256 * k, &SS[cur ^ 1][16 + 64 * wid + 256 * k]);
        }

        // Taps -> SGPR (uniform LDS broadcast reads + readfirstlane).
        float hre[TAPS], him[TAPS];
        #pragma unroll
        for (int l = 0; l < TAPS; ++l) {
            float2 tv = s_tap[it][l];
            hre[l] = rfl(tv.x);
            him[l] = rfl(tv.y);
        }

        const float4* S4 = &SS[cur][0];
        float2* go2 = (float2*)(out0 + r * (size_t)(OUTLEN * 2));

        // ---- main: r11 core verbatim (W=2 x 4 groups, 16B-stride reads) ----
        #pragma unroll 1
        for (int j = 0; j < 4; ++j) {
            const int t0 = 2 * tid + 1 + 512 * j;

            v2f accA[2], accB[2];
            #pragma unroll
            for (int k = 0; k < 2; ++k) { accA[k] = (v2f)(0.f); accB[k] = (v2f)(0.f); }

            #pragma unroll
            for (int c = 0; c < 4; ++c) {
                const int base4 = tid + 13 + 256 * j - 4 * c;
                float4 w4[5];
                #pragma unroll
                for (int i = 0; i < 5; ++i) w4[i] = S4[base4 + i];

                #pragma unroll
                for (int lp = 0; lp < 8; ++lp) {
                    const int l = 8 * c + lp;
                    const v2f hv = { hre[l], him[l] };     // SGPR pair, uniform
                    #pragma unroll
                    for (int k = 0; k < 2; ++k) {
                        const int m = k - lp + 7;          // 0..8, compile-time
                        const float sx = (m & 1) ? w4[m >> 1].z : w4[m >> 1].x;
                        const float sy = (m & 1) ? w4[m >> 1].w : w4[m >> 1].y;
                        accA[k] = __builtin_elementwise_fma((v2f){ sx, sx }, hv, accA[k]);
                        accB[k] = __builtin_elementwise_fma((v2f){ sy, sy }, hv, accB[k]);
                    }
                }
                __builtin_amdgcn_sched_barrier(0);   // contain chunk live-ranges
            }

            go2[t0]     = make_float2(accA[0].x - accB[0].y, accA[0].y + accB[0].x);
            go2[t0 + 1] = make_float2(accA[1].x - accB[1].y, accA[1].y + accB[1].x);
        }

        const float2* S2 = (const float2*)S4;

        // ---- wave 0: fused 64-pt DFT of zero-padded taps ----
        if (tid < MDFT) {
            const int kk = tid;
            v2f aA = (v2f)(0.f), aB = (v2f)(0.f);
            #pragma unroll
            for (int l = 0; l < TAPS; ++l) {
                const v2f hv = { hre[l], him[l] };
                float2 w = s_tw[(kk * l) & (MDFT - 1)];
                aA = __builtin_elementwise_fma((v2f){ w.x, w.x }, hv, aA);
                aB = __builtin_elementwise_fma((v2f){ w.y, w.y }, hv, aB);
            }
            ((float2*)out1)[r * MDFT + kk] = make_float2(aA.x - aB.y, aA.y + aB.x);
        }
        // ---- wave 2: leftover outputs t=0 and t=2049..2078 ----
        else if (tid >= 128 && tid <= 158) {
            const int t = (tid == 158) ? 0 : (2049 + (tid - 128));
            v2f aA = (v2f)(0.f), aB = (v2f)(0.f);
            #pragma unroll
            for (int l = 0; l < TAPS; ++l) {
                const v2f hv = { hre[l], him[l] };
                float2 s = S2[PAD + t - l];      // pads supply zeros both ends
                aA = __builtin_elementwise_fma((v2f){ s.x, s.x }, hv, aA);
                aB = __builtin_elementwise_fma((v2f){ s.y, s.y }, hv, aB);
            }
            go2[t] = make_float2(aA.x - aB.y, aA.y + aB.x);
        }

        cur ^= 1;
    }
}

extern "C" void kernel_launch(void* const* d_in, const int* in_sizes, int n_in,
                              void* d_out, int out_size, void* d_ws, size_t ws_size,
                              hipStream_t stream)
{
    const float* input = (const float*)d_in[0];  // (N,P,2048,2) fp32
    const float* cof   = (const float*)d_in[1];  // (N,P,32,2)   fp32
    // d_in[2] is M (=64), compile-time here.

    float* out0 = (float*)d_out;                                   // (NP, 2079, 2)
    const int NP = in_sizes[0] / (SMK * 2);                        // 16384
    float* out1 = out0 + (size_t)NP * OUTLEN * 2;                  // (NP, 64, 2)

    conv_kernel<<<NBLOCKS, 256, 0, stream>>>(input, cof, out0, out1);
}